// Round 1
// baseline (255.584 us; speedup 1.0000x reference)
//
#include <hip/hip_runtime.h>
#include <hip/hip_bf16.h>

typedef __attribute__((ext_vector_type(8))) short short8;
typedef __attribute__((ext_vector_type(4))) float f32x4;

#define B_SZ 32
#define T_SZ 4096
#define H_SZ 512
#define NROWS (B_SZ * T_SZ)   // 131072

static __device__ __forceinline__ unsigned short f2bf(float f) {
  unsigned int u = __float_as_uint(f);
  u += 0x7fffu + ((u >> 16) & 1u);   // round-to-nearest-even
  return (unsigned short)(u >> 16);
}

static __device__ __forceinline__ float fast_tanh(float x) {
  // overflow-safe: exp(2|x|) -> inf gives t -> 1 (correct saturation)
  float ax = fabsf(x);
  float e  = __expf(2.0f * ax);
  float t  = 1.0f - 2.0f / (e + 1.0f);
  return copysignf(t, x);
}

// ---- W fp32 -> bf16 (262144 elems, 4/thread) ----
__global__ __launch_bounds__(256) void convert_w_kernel(
    const float* __restrict__ W, unsigned short* __restrict__ Wb) {
  int i = blockIdx.x * 256 + threadIdx.x;       // 65536 quads
  float4 wv = reinterpret_cast<const float4*>(W)[i];
  ushort4 h;
  h.x = f2bf(wv.x); h.y = f2bf(wv.y); h.z = f2bf(wv.z); h.w = f2bf(wv.w);
  reinterpret_cast<ushort4*>(Wb)[i] = h;
}

// ---- scores[row] = sum_g v[g] * tanh( X[row,:] . W[g,:] )  via bf16 MFMA ----
// block: 256 thr = 4 waves, each wave owns 16 rows; M_tile=64, N chunks of 16, K=512
__global__ __launch_bounds__(256) void score_kernel(
    const float* __restrict__ X, const unsigned short* __restrict__ Wb,
    const float* __restrict__ v, float* __restrict__ scores) {
  __shared__ unsigned char XsB[64 * 1024];   // 64 rows x 512 bf16, XOR-swizzled
  __shared__ unsigned char WsB[16 * 1024];   // 16 g-rows x 512 bf16, XOR-swizzled

  const int tid   = threadIdx.x;
  const int lane  = tid & 63;
  const int wave  = tid >> 6;
  const int frow  = lane & 15;   // A: m index / B: n (g) index
  const int kslot = lane >> 4;   // selects k-subrange 8*kslot..+7
  const size_t rowbase = (size_t)blockIdx.x * 64;

  // stage X tile: 64x512 fp32 -> bf16 in LDS (swizzle byte ^= (row&7)<<4)
  {
    const float4* Xt = reinterpret_cast<const float4*>(X + rowbase * H_SZ);
    #pragma unroll
    for (int i = 0; i < 32; ++i) {
      int idx = tid + (i << 8);        // 0..8191 float4 units
      int row = idx >> 7;              // 128 float4 per row
      int c4  = idx & 127;
      float4 xv = Xt[idx];
      ushort4 h;
      h.x = f2bf(xv.x); h.y = f2bf(xv.y); h.z = f2bf(xv.z); h.w = f2bf(xv.w);
      int boff = (c4 << 3) ^ ((row & 7) << 4);
      *reinterpret_cast<ushort4*>(XsB + row * 1024 + boff) = h;
    }
  }

  float sc0 = 0.f, sc1 = 0.f, sc2 = 0.f, sc3 = 0.f;

  const int arow = wave * 16 + frow;
  const unsigned char* ap = XsB + arow * 1024;
  const int aswz = (arow & 7) << 4;
  const unsigned char* bp = WsB + frow * 1024;
  const int bswz = (frow & 7) << 4;

  for (int nb = 0; nb < 512; nb += 16) {
    __syncthreads();   // covers Xs staging (first iter) + Ws reuse (later iters)
    // stage W chunk: contiguous 16 KB from Wb + nb*512, swizzled per row
    {
      const uint4* Wt = reinterpret_cast<const uint4*>(Wb + nb * H_SZ);
      #pragma unroll
      for (int i = 0; i < 4; ++i) {
        int off = (tid << 4) + (i << 12);   // byte 0..16383
        uint4 wv = Wt[off >> 4];
        int row = off >> 10;
        int col = off & 1023;
        *reinterpret_cast<uint4*>(WsB + row * 1024 + (col ^ ((row & 7) << 4))) = wv;
      }
    }
    __syncthreads();

    f32x4 acc = {0.f, 0.f, 0.f, 0.f};
    #pragma unroll
    for (int k0 = 0; k0 < 512; k0 += 32) {
      int off = (k0 << 1) + (kslot << 4);
      short8 a = *reinterpret_cast<const short8*>(ap + (off ^ aswz));
      short8 b = *reinterpret_cast<const short8*>(bp + (off ^ bswz));
      acc = __builtin_amdgcn_mfma_f32_16x16x32_bf16(a, b, acc, 0, 0, 0);
    }
    // epilogue for this g-chunk: D[m][n], n = frow, m = kslot*4 + reg
    float vg = v[nb + frow];
    sc0 += vg * fast_tanh(acc[0]);
    sc1 += vg * fast_tanh(acc[1]);
    sc2 += vg * fast_tanh(acc[2]);
    sc3 += vg * fast_tanh(acc[3]);
  }

  // reduce over the 16 n-lanes sharing the same kslot group
  #pragma unroll
  for (int d = 1; d < 16; d <<= 1) {
    sc0 += __shfl_xor(sc0, d);
    sc1 += __shfl_xor(sc1, d);
    sc2 += __shfl_xor(sc2, d);
    sc3 += __shfl_xor(sc3, d);
  }
  if (frow == 0) {
    float* sp = scores + rowbase + wave * 16 + kslot * 4;
    sp[0] = sc0; sp[1] = sc1; sp[2] = sc2; sp[3] = sc3;
  }
}

// ---- per-b softmax stats; rewrites scores in place with unnormalized exp ----
__global__ __launch_bounds__(256) void softmax_kernel(
    float* __restrict__ scores, float* __restrict__ denom) {
  const int b = blockIdx.x;
  float* s = scores + b * T_SZ;
  const int tid = threadIdx.x;
  __shared__ float redm[4], reds[4];

  float m = -1e30f;
  for (int t = tid; t < T_SZ; t += 256) m = fmaxf(m, s[t]);
  #pragma unroll
  for (int d = 1; d < 64; d <<= 1) m = fmaxf(m, __shfl_xor(m, d));
  if ((tid & 63) == 0) redm[tid >> 6] = m;
  __syncthreads();
  m = fmaxf(fmaxf(redm[0], redm[1]), fmaxf(redm[2], redm[3]));

  float sum = 0.f;
  for (int t = tid; t < T_SZ; t += 256) {
    float u = __expf(s[t] - m);
    s[t] = u;
    sum += u;
  }
  #pragma unroll
  for (int d = 1; d < 64; d <<= 1) sum += __shfl_xor(sum, d);
  if ((tid & 63) == 0) reds[tid >> 6] = sum;
  __syncthreads();
  if (tid == 0) denom[b] = reds[0] + reds[1] + reds[2] + reds[3];
}

// ---- partial weighted sums: partial[b][ch][h] = sum_{t in chunk} u_t * x[b,t,h] ----
__global__ __launch_bounds__(256) void wsum_kernel(
    const float* __restrict__ X, const float* __restrict__ u,
    float* __restrict__ partial) {
  const int ch = blockIdx.x;   // 32 chunks of 128 t
  const int b  = blockIdx.y;   // 32
  const float* xb = X + ((size_t)b * T_SZ + ch * 128) * H_SZ;
  const float* ub = u + b * T_SZ + ch * 128;
  const int h2 = threadIdx.x;  // float2 index, 256 threads cover 512 h
  float ax = 0.f, ay = 0.f;
  for (int tt = 0; tt < 128; ++tt) {
    float w = ub[tt];
    float2 xv = reinterpret_cast<const float2*>(xb + (size_t)tt * H_SZ)[h2];
    ax = fmaf(w, xv.x, ax);
    ay = fmaf(w, xv.y, ay);
  }
  float2 r; r.x = ax; r.y = ay;
  reinterpret_cast<float2*>(partial + ((size_t)b * 32 + ch) * H_SZ)[h2] = r;
}

// ---- out[b][h] = (1/denom_b) * sum_ch partial[b][ch][h] ----
__global__ __launch_bounds__(256) void finalize_kernel(
    const float* __restrict__ partial, const float* __restrict__ denom,
    float* __restrict__ out) {
  const int b = blockIdx.x;
  const float inv = 1.0f / denom[b];
  for (int h = threadIdx.x; h < H_SZ; h += 256) {
    float s = 0.f;
    #pragma unroll
    for (int c = 0; c < 32; ++c) s += partial[((size_t)b * 32 + c) * H_SZ + h];
    out[b * H_SZ + h] = s * inv;
  }
}

extern "C" void kernel_launch(void* const* d_in, const int* in_sizes, int n_in,
                              void* d_out, int out_size, void* d_ws, size_t ws_size,
                              hipStream_t stream) {
  const float* X = (const float*)d_in[0];   // (32,4096,512)
  const float* W = (const float*)d_in[1];   // (512,512)
  const float* v = (const float*)d_in[2];   // (512,)
  float* out = (float*)d_out;               // (32,512) fp32
  unsigned char* ws = (unsigned char*)d_ws;

  unsigned short* Wb   = (unsigned short*)(ws);                 // 512 KB
  float* scores        = (float*)(ws + (512u << 10));           // 512 KB (becomes u)
  float* denom         = (float*)(ws + (1024u << 10));          // 128 B
  float* partial       = (float*)(ws + (1024u << 10) + 512);    // 2 MB

  convert_w_kernel<<<256, 256, 0, stream>>>(W, Wb);
  score_kernel<<<NROWS / 64, 256, 0, stream>>>(X, Wb, v, scores);
  softmax_kernel<<<B_SZ, 256, 0, stream>>>(scores, denom);
  dim3 g(32, B_SZ);
  wsum_kernel<<<g, 256, 0, stream>>>(X, scores, partial);
  finalize_kernel<<<B_SZ, 256, 0, stream>>>(partial, denom, out);
}

// Round 2
// 169.362 us; speedup vs baseline: 1.5091x; 1.5091x over previous
//
#include <hip/hip_runtime.h>
#include <hip/hip_bf16.h>

typedef __attribute__((ext_vector_type(8))) short short8;
typedef __attribute__((ext_vector_type(4))) float f32x4;

#define B_SZ 32
#define T_SZ 4096
#define H_SZ 512
#define NROWS (B_SZ * T_SZ)   // 131072

static __device__ __forceinline__ unsigned short f2bf(float f) {
  unsigned int u = __float_as_uint(f);
  u += 0x7fffu + ((u >> 16) & 1u);   // round-to-nearest-even
  return (unsigned short)(u >> 16);
}
static __device__ __forceinline__ unsigned int pack2(float a, float b) {
  return (unsigned int)f2bf(a) | ((unsigned int)f2bf(b) << 16);
}
static __device__ __forceinline__ float fast_tanh(float x) {
  float ax = fabsf(x);
  float e  = __expf(2.0f * ax);
  float t  = 1.0f - 2.0f / (e + 1.0f);
  return copysignf(t, x);
}

// ---- W fp32 (512x512) -> bf16 in MFMA-fragment order ----
// fragment s = grow*64 + kt*4 + kslot; holds W[grow][kt*32 + kslot*8 .. +8]
// dst uint4 index = nb*1024 + kt*64 + (kslot*16 + g)   (nb=grow/16, g=grow%16)
// so a 16-g chunk is a contiguous 16 KB block in [kt][lane] order.
__global__ __launch_bounds__(256) void prep_w_kernel(
    const float* __restrict__ W, uint4* __restrict__ Wfrag) {
  int s = blockIdx.x * 256 + threadIdx.x;   // 0..32767
  int grow  = s >> 6;
  int kt    = (s >> 2) & 15;
  int kslot = s & 3;
  const float4* Wf4 = reinterpret_cast<const float4*>(W);
  float4 lo = Wf4[grow * 128 + kt * 8 + kslot * 2];
  float4 hi = Wf4[grow * 128 + kt * 8 + kslot * 2 + 1];
  uint4 u;
  u.x = pack2(lo.x, lo.y); u.y = pack2(lo.z, lo.w);
  u.z = pack2(hi.x, hi.y); u.w = pack2(hi.z, hi.w);
  int nb = grow >> 4, g = grow & 15;
  Wfrag[nb * 1024 + kt * 64 + kslot * 16 + g] = u;
}

// ---- scores[row] = sum_g v[g] * tanh( X[row,:] . W[g,:] ) ----
// 256 thr = 4 waves, wave owns 16 rows (M_tile=64). A in registers (full K),
// B double-buffered 16 KB LDS chunks staged via global_load_lds (linear).
__global__ __launch_bounds__(256, 4) void score_kernel(
    const float* __restrict__ X, const uint4* __restrict__ Wfrag,
    const float* __restrict__ v, float* __restrict__ scores) {
  __shared__ unsigned char WsB[2][16384];

  const int tid   = threadIdx.x;
  const int lane  = tid & 63;
  const int wave  = tid >> 6;
  const int frow  = lane & 15;   // A: m row / B: g col
  const int kslot = lane >> 4;
  const size_t rowbase = (size_t)blockIdx.x * 64;
  const size_t arow = rowbase + wave * 16 + frow;

  // A fragments: X[arow][kt*32 + kslot*8 .. +8] for kt=0..15, bf16-packed
  short8 afrag[16];
  {
    const float4* xr = reinterpret_cast<const float4*>(X + arow * H_SZ);
    #pragma unroll
    for (int kt = 0; kt < 16; ++kt) {
      float4 lo = xr[kt * 8 + kslot * 2];
      float4 hi = xr[kt * 8 + kslot * 2 + 1];
      union { uint4 u; short8 s; } cv;
      cv.u.x = pack2(lo.x, lo.y); cv.u.y = pack2(lo.z, lo.w);
      cv.u.z = pack2(hi.x, hi.y); cv.u.w = pack2(hi.z, hi.w);
      afrag[kt] = cv.s;
    }
  }

  // prologue: stage chunk 0 into buf 0 (linear 16 KB copy, 4 KB per wave)
  {
    const char* src = (const char*)Wfrag + wave * 4096 + lane * 16;
    unsigned char* dst = &WsB[0][wave * 4096];
    #pragma unroll
    for (int i = 0; i < 4; ++i)
      __builtin_amdgcn_global_load_lds((const unsigned int*)(src + i * 1024),
                                       (unsigned int*)(dst + i * 1024), 16, 0, 0);
  }
  __syncthreads();

  float sc0 = 0.f, sc1 = 0.f, sc2 = 0.f, sc3 = 0.f;
  int cur = 0;
  for (int nb = 0; nb < 32; ++nb) {
    if (nb < 31) {   // stage next chunk into the other buffer
      const char* src = (const char*)Wfrag + (size_t)(nb + 1) * 16384 + wave * 4096 + lane * 16;
      unsigned char* dst = &WsB[cur ^ 1][wave * 4096];
      #pragma unroll
      for (int i = 0; i < 4; ++i)
        __builtin_amdgcn_global_load_lds((const unsigned int*)(src + i * 1024),
                                         (unsigned int*)(dst + i * 1024), 16, 0, 0);
    }
    float vg = v[nb * 16 + frow];   // issued early, L1-broadcast

    f32x4 acc = {0.f, 0.f, 0.f, 0.f};
    const unsigned char* bbase = &WsB[cur][lane * 16];
    #pragma unroll
    for (int kt = 0; kt < 16; ++kt) {
      short8 b = *reinterpret_cast<const short8*>(bbase + kt * 1024);  // linear, conflict-free
      acc = __builtin_amdgcn_mfma_f32_16x16x32_bf16(afrag[kt], b, acc, 0, 0, 0);
    }
    // D[m][n]: n = frow (g), m = kslot*4 + reg
    sc0 += vg * fast_tanh(acc[0]);
    sc1 += vg * fast_tanh(acc[1]);
    sc2 += vg * fast_tanh(acc[2]);
    sc3 += vg * fast_tanh(acc[3]);

    __syncthreads();   // drains stage vmcnt; next buffer ready
    cur ^= 1;
  }

  // reduce over the 16 g-lanes (frow) within each kslot group
  #pragma unroll
  for (int d = 1; d < 16; d <<= 1) {
    sc0 += __shfl_xor(sc0, d);
    sc1 += __shfl_xor(sc1, d);
    sc2 += __shfl_xor(sc2, d);
    sc3 += __shfl_xor(sc3, d);
  }
  if (frow == 0) {
    float* sp = scores + rowbase + wave * 16 + kslot * 4;
    sp[0] = sc0; sp[1] = sc1; sp[2] = sc2; sp[3] = sc3;
  }
}

// ---- per-b softmax stats; rewrites scores in place with unnormalized exp ----
__global__ __launch_bounds__(256) void softmax_kernel(
    float* __restrict__ scores, float* __restrict__ denom) {
  const int b = blockIdx.x;
  float* s = scores + b * T_SZ;
  const int tid = threadIdx.x;
  __shared__ float redm[4], reds[4];

  float m = -1e30f;
  for (int t = tid; t < T_SZ; t += 256) m = fmaxf(m, s[t]);
  #pragma unroll
  for (int d = 1; d < 64; d <<= 1) m = fmaxf(m, __shfl_xor(m, d));
  if ((tid & 63) == 0) redm[tid >> 6] = m;
  __syncthreads();
  m = fmaxf(fmaxf(redm[0], redm[1]), fmaxf(redm[2], redm[3]));

  float sum = 0.f;
  for (int t = tid; t < T_SZ; t += 256) {
    float u = __expf(s[t] - m);
    s[t] = u;
    sum += u;
  }
  #pragma unroll
  for (int d = 1; d < 64; d <<= 1) sum += __shfl_xor(sum, d);
  if ((tid & 63) == 0) reds[tid >> 6] = sum;
  __syncthreads();
  if (tid == 0) denom[b] = reds[0] + reds[1] + reds[2] + reds[3];
}

// ---- partial[b][ch][h] = sum_{t in chunk} u_t * x[b,t,h] ----
__global__ __launch_bounds__(256) void wsum_kernel(
    const float* __restrict__ X, const float* __restrict__ u,
    float* __restrict__ partial) {
  const int ch = blockIdx.x;   // 32 chunks of 128 t
  const int b  = blockIdx.y;   // 32
  const float* xb = X + ((size_t)b * T_SZ + ch * 128) * H_SZ;
  const float* ub = u + b * T_SZ + ch * 128;
  const int h2 = threadIdx.x;  // float2 index
  float ax = 0.f, ay = 0.f;
  for (int tt = 0; tt < 128; ++tt) {
    float w = ub[tt];
    float2 xv = reinterpret_cast<const float2*>(xb + (size_t)tt * H_SZ)[h2];
    ax = fmaf(w, xv.x, ax);
    ay = fmaf(w, xv.y, ay);
  }
  float2 r; r.x = ax; r.y = ay;
  reinterpret_cast<float2*>(partial + ((size_t)b * 32 + ch) * H_SZ)[h2] = r;
}

// ---- out[b][h] = (1/denom_b) * sum_ch partial[b][ch][h] ----
__global__ __launch_bounds__(256) void finalize_kernel(
    const float* __restrict__ partial, const float* __restrict__ denom,
    float* __restrict__ out) {
  const int b = blockIdx.x;
  const float inv = 1.0f / denom[b];
  for (int h = threadIdx.x; h < H_SZ; h += 256) {
    float s = 0.f;
    #pragma unroll
    for (int c = 0; c < 32; ++c) s += partial[((size_t)b * 32 + c) * H_SZ + h];
    out[b * H_SZ + h] = s * inv;
  }
}

extern "C" void kernel_launch(void* const* d_in, const int* in_sizes, int n_in,
                              void* d_out, int out_size, void* d_ws, size_t ws_size,
                              hipStream_t stream) {
  const float* X = (const float*)d_in[0];   // (32,4096,512)
  const float* W = (const float*)d_in[1];   // (512,512)
  const float* v = (const float*)d_in[2];   // (512,)
  float* out = (float*)d_out;               // (32,512) fp32
  unsigned char* ws = (unsigned char*)d_ws;

  uint4* Wfrag   = (uint4*)(ws);                        // 512 KB
  float* scores  = (float*)(ws + (512u << 10));         // 512 KB (becomes u)
  float* denom   = (float*)(ws + (1024u << 10));        // 128 B
  float* partial = (float*)(ws + (1024u << 10) + 512);  // 2 MB

  prep_w_kernel<<<128, 256, 0, stream>>>(W, Wfrag);
  score_kernel<<<NROWS / 64, 256, 0, stream>>>(X, Wfrag, v, scores);
  softmax_kernel<<<B_SZ, 256, 0, stream>>>(scores, denom);
  dim3 g(32, B_SZ);
  wsum_kernel<<<g, 256, 0, stream>>>(X, scores, partial);
  finalize_kernel<<<B_SZ, 256, 0, stream>>>(partial, denom, out);
}